// Round 1
// baseline (514.042 us; speedup 1.0000x reference)
//
#include <hip/hip_runtime.h>

typedef __attribute__((ext_vector_type(4))) float f32x4;
typedef __attribute__((ext_vector_type(8))) __bf16 bf16x8;
typedef __attribute__((ext_vector_type(4))) __bf16 bf16x4;

#define MFMA16(a, b, c) __builtin_amdgcn_mfma_f32_16x16x32_bf16((a), (b), (c), 0, 0, 0)

// LDS element-index swizzle: row c (0..31, pitch 1024 bf16 = 2048B), elem i (0..1023).
// XOR of 16B-slot index with (c&7) spreads the 16 rows of a B-fragment read
// across 8 bank-quads -> 2-way (free) instead of 16-way conflict.
__device__ __forceinline__ int swz(int c, int i) {
  return (c << 10) + (i ^ ((c & 7) << 3));
}

__global__ void prep_gso(const float* __restrict__ g, __bf16* __restrict__ gb) {
  int i = (blockIdx.x * 256 + threadIdx.x) * 4;
  float4 v = *reinterpret_cast<const float4*>(g + i);
  bf16x4 h;
  h[0] = (__bf16)v.x; h[1] = (__bf16)v.y; h[2] = (__bf16)v.z; h[3] = (__bf16)v.w;
  *reinterpret_cast<bf16x4*>(gb + i) = h;
}

// Wt[k][j][c] = weight[k][c][j] * (k==1 ? 0.5 : 1)   (transposed so the MFMA
// B-fragment (8 contiguous k=c elems at fixed output col j) is a 16B load).
// W1 is pre-halved because we store Y1s = 2*X1 in LDS (feeds GEMM2 directly).
__global__ void prep_w(const float* __restrict__ w, __bf16* __restrict__ wt) {
  int tid = blockIdx.x * 256 + threadIdx.x;
  if (tid < 3 * 32 * 32) {
    int k = tid >> 10, rem = tid & 1023;
    int j = rem >> 5, c = rem & 31;
    float s = (k == 1) ? 0.5f : 1.0f;
    wt[tid] = (__bf16)(w[(k * 32 + c) * 32 + j] * s);
  }
}

__global__ __launch_bounds__(512, 2)
void cheb_fused(const float* __restrict__ x, const __bf16* __restrict__ Gb,
                const __bf16* __restrict__ Wt, const float* __restrict__ bias,
                float* __restrict__ out)
{
  __shared__ __bf16 ldsX[32 * 1024];  // X0 (later overwritten by Y2, per-wave slice)
  __shared__ __bf16 ldsY[32 * 1024];  // Y1s = 2*X1

  const int wg = blockIdx.x;          // wg = b*64 + t
  const int b = wg >> 6, t = wg & 63;
  const int tid = threadIdx.x;
  const int lane = tid & 63;
  const int wid = tid >> 6;           // 0..7, wave owns rows [wid*128, wid*128+128)
  const int l15 = lane & 15;
  const int lg = lane >> 4;           // 0..3

  // ---- stage X0 = x[b, :, t, :]  ->  ldsX[c][i] (bf16, swizzled) ----
  {
    const int c = tid >> 4;           // 16 threads per channel row
    const int seg = tid & 15;
    const float* xr = x + (size_t)((b * 32 + c) * 64 + t) * 1024;
    #pragma unroll
    for (int g = 0; g < 8; ++g) {
      int i0 = g * 128 + seg * 8;
      float4 v0 = *reinterpret_cast<const float4*>(xr + i0);
      float4 v1 = *reinterpret_cast<const float4*>(xr + i0 + 4);
      bf16x8 h;
      h[0] = (__bf16)v0.x; h[1] = (__bf16)v0.y; h[2] = (__bf16)v0.z; h[3] = (__bf16)v0.w;
      h[4] = (__bf16)v1.x; h[5] = (__bf16)v1.y; h[6] = (__bf16)v1.z; h[7] = (__bf16)v1.w;
      *reinterpret_cast<bf16x8*>(&ldsX[swz(c, i0)]) = h;
    }
  }
  __syncthreads();

  const f32x4 zero = {0.f, 0.f, 0.f, 0.f};
  f32x4 acc[8][2];
  #pragma unroll
  for (int r = 0; r < 8; ++r) { acc[r][0] = zero; acc[r][1] = zero; }

  // A-fragment base: lane holds G row (wid*128 + r*16 + l15), k-elems lg*8..+7
  const __bf16* Ga = Gb + (size_t)(wid * 128 + l15) * 1024 + lg * 8;

  // ---- GEMM1: X1[h,c] = sum_i G[h,i] * X0[i,c]  (M=1024, N=32, K=1024) ----
  #pragma unroll 2
  for (int k = 0; k < 1024; k += 32) {
    bf16x8 bf0 = *reinterpret_cast<const bf16x8*>(&ldsX[swz(l15, k + lg * 8)]);
    bf16x8 bf1 = *reinterpret_cast<const bf16x8*>(&ldsX[swz(16 + l15, k + lg * 8)]);
    bf16x8 af[8];
    #pragma unroll
    for (int r = 0; r < 8; ++r)
      af[r] = *reinterpret_cast<const bf16x8*>(Ga + r * 16 * 1024 + k);
    #pragma unroll
    for (int r = 0; r < 8; ++r) {
      acc[r][0] = MFMA16(af[r], bf0, acc[r][0]);
      acc[r][1] = MFMA16(af[r], bf1, acc[r][1]);
    }
  }

  // ---- write Y1s = 2*X1 to ldsY (bf16, transposed [c][h], swizzled) ----
  #pragma unroll
  for (int r = 0; r < 8; ++r) {
    int hb = wid * 128 + r * 16 + lg * 4;
    #pragma unroll
    for (int cf = 0; cf < 2; ++cf) {
      int c = cf * 16 + l15;
      bf16x4 p;
      #pragma unroll
      for (int q = 0; q < 4; ++q) p[q] = (__bf16)(2.0f * acc[r][cf][q]);
      *reinterpret_cast<bf16x4*>(&ldsY[swz(c, hb)]) = p;
    }
  }
  __syncthreads();

  // ---- GEMM2: X2[h,c] = sum_i G[h,i] * Y1s[i,c] - X0[h,c] ----
  #pragma unroll
  for (int r = 0; r < 8; ++r) {
    int hb = wid * 128 + r * 16 + lg * 4;
    #pragma unroll
    for (int cf = 0; cf < 2; ++cf) {
      int c = cf * 16 + l15;
      bf16x4 xv = *reinterpret_cast<const bf16x4*>(&ldsX[swz(c, hb)]);
      f32x4 a;
      #pragma unroll
      for (int q = 0; q < 4; ++q) a[q] = -(float)xv[q];
      acc[r][cf] = a;
    }
  }
  #pragma unroll 2
  for (int k = 0; k < 1024; k += 32) {
    bf16x8 bf0 = *reinterpret_cast<const bf16x8*>(&ldsY[swz(l15, k + lg * 8)]);
    bf16x8 bf1 = *reinterpret_cast<const bf16x8*>(&ldsY[swz(16 + l15, k + lg * 8)]);
    bf16x8 af[8];
    #pragma unroll
    for (int r = 0; r < 8; ++r)
      af[r] = *reinterpret_cast<const bf16x8*>(Ga + r * 16 * 1024 + k);
    #pragma unroll
    for (int r = 0; r < 8; ++r) {
      acc[r][0] = MFMA16(af[r], bf0, acc[r][0]);
      acc[r][1] = MFMA16(af[r], bf1, acc[r][1]);
    }
  }

  // ---- out[h,j] = X0@W0 + Y1s@(W1/2) + Y2@W2 + bias ----
  f32x4 oacc[8][2];
  {
    float b0 = bias[l15], b1 = bias[16 + l15];
    f32x4 v0 = {b0, b0, b0, b0}, v1 = {b1, b1, b1, b1};
    #pragma unroll
    for (int r = 0; r < 8; ++r) { oacc[r][0] = v0; oacc[r][1] = v1; }
  }

  auto contrib = [&](const __bf16* lds, const __bf16* wtk) {
    bf16x8 w0 = *reinterpret_cast<const bf16x8*>(wtk + l15 * 32 + lg * 8);
    bf16x8 w1 = *reinterpret_cast<const bf16x8*>(wtk + (16 + l15) * 32 + lg * 8);
    #pragma unroll
    for (int r = 0; r < 8; ++r) {
      int h = wid * 128 + r * 16 + l15;
      bf16x8 af;
      #pragma unroll
      for (int j = 0; j < 8; ++j) af[j] = lds[swz(lg * 8 + j, h)];
      oacc[r][0] = MFMA16(af, w0, oacc[r][0]);
      oacc[r][1] = MFMA16(af, w1, oacc[r][1]);
    }
  };

  contrib(ldsX, Wt);            // k=0 (X0)

  // overwrite this wave's own X0 columns with Y2 (column-disjoint across waves,
  // wave-local read-after-write -> no barrier needed, lgkmcnt ordering suffices)
  #pragma unroll
  for (int r = 0; r < 8; ++r) {
    int hb = wid * 128 + r * 16 + lg * 4;
    #pragma unroll
    for (int cf = 0; cf < 2; ++cf) {
      int c = cf * 16 + l15;
      bf16x4 p;
      #pragma unroll
      for (int q = 0; q < 4; ++q) p[q] = (__bf16)acc[r][cf][q];
      *reinterpret_cast<bf16x4*>(&ldsX[swz(c, hb)]) = p;
    }
  }

  contrib(ldsY, Wt + 1024);     // k=1 (Y1s with pre-halved W1)
  contrib(ldsX, Wt + 2048);     // k=2 (Y2)

  // ---- store ----
  float* ob = out + (size_t)wg * 32768;
  #pragma unroll
  for (int r = 0; r < 8; ++r) {
    int hb = wid * 128 + r * 16 + lg * 4;
    #pragma unroll
    for (int q = 0; q < 4; ++q) {
      ob[(hb + q) * 32 + l15] = oacc[r][0][q];
      ob[(hb + q) * 32 + 16 + l15] = oacc[r][1][q];
    }
  }
}

extern "C" void kernel_launch(void* const* d_in, const int* in_sizes, int n_in,
                              void* d_out, int out_size, void* d_ws, size_t ws_size,
                              hipStream_t stream) {
  const float* x    = (const float*)d_in[0];
  const float* gso  = (const float*)d_in[1];
  const float* w    = (const float*)d_in[2];
  const float* bias = (const float*)d_in[3];
  float* out = (float*)d_out;

  __bf16* Gb = (__bf16*)d_ws;           // 1024*1024 bf16 = 2 MB
  __bf16* Wt = Gb + 1024 * 1024;        // 3*32*32 bf16

  prep_gso<<<1024, 256, 0, stream>>>(gso, Gb);
  prep_w<<<12, 256, 0, stream>>>(w, Wt);
  cheb_fused<<<1024, 512, 0, stream>>>(x, Gb, Wt, bias, out);
}

// Round 2
// 269.987 us; speedup vs baseline: 1.9039x; 1.9039x over previous
//
#include <hip/hip_runtime.h>

typedef __attribute__((ext_vector_type(4))) float f32x4;
typedef __attribute__((ext_vector_type(8))) __bf16 bf16x8;
typedef __attribute__((ext_vector_type(4))) __bf16 bf16x4;

#define MFMA16(a, b, c) __builtin_amdgcn_mfma_f32_16x16x32_bf16((a), (b), (c), 0, 0, 0)

typedef const __attribute__((address_space(1))) void* gas1_t;
typedef __attribute__((address_space(3))) void* las3_t;
#define GLOAD16(gp, lp) __builtin_amdgcn_global_load_lds((gas1_t)(gp), (las3_t)(lp), 16, 0, 0)

// ---------------- prep kernels ----------------

__global__ void prep_gso(const float* __restrict__ g, __bf16* __restrict__ gb) {
  int i = (blockIdx.x * 256 + threadIdx.x) * 4;
  float4 v = *reinterpret_cast<const float4*>(g + i);
  bf16x4 h;
  h[0] = (__bf16)v.x; h[1] = (__bf16)v.y; h[2] = (__bf16)v.z; h[3] = (__bf16)v.w;
  *reinterpret_cast<bf16x4*>(gb + i) = h;
}

// wt[k][j][c]: k0 = W0 - W2 (Chebyshev -X0 fold), k1 = W1/2 (X1 stored as 2*X1), k2 = W2
__global__ void prep_w3(const float* __restrict__ w, __bf16* __restrict__ wt) {
  int tid = blockIdx.x * 256 + threadIdx.x;
  if (tid < 3072) {
    int k = tid >> 10, rem = tid & 1023, j = rem >> 5, c = rem & 31;
    float wk = w[k * 1024 + c * 32 + j];
    float v;
    if (k == 0)      v = wk - w[2 * 1024 + c * 32 + j];
    else if (k == 1) v = 0.5f * wk;
    else             v = wk;
    wt[tid] = (__bf16)v;
  }
}

// X0t[(b*64+t)*32 + c][i] = x[b][c][t][i]  (row permutation + f32->bf16)
__global__ __launch_bounds__(256) void k0_transpose(const float* __restrict__ x,
                                                    __bf16* __restrict__ X0t) {
  int n0 = blockIdx.x * 8;
  int tid = threadIdx.x;
  #pragma unroll
  for (int r = 0; r < 8; ++r) {
    int n = n0 + r;
    int b = n >> 11, t = (n >> 5) & 63, c = n & 31;
    const float* src = x + (size_t)((b * 32 + c) * 64 + t) * 1024;
    float4 v = *reinterpret_cast<const float4*>(&src[tid * 4]);
    bf16x4 p;
    p[0] = (__bf16)v.x; p[1] = (__bf16)v.y; p[2] = (__bf16)v.z; p[3] = (__bf16)v.w;
    *reinterpret_cast<bf16x4*>(&X0t[(size_t)n * 1024 + tid * 4]) = p;
  }
}

// ---------------- main GEMM (m97-style 128x128 tile, BK=32) ----------------
// C[h][n] = sum_i Gb[h][i] * Bmat[n][i]    (both operands k-contiguous)
// MODE 0: store X1t[n][h] = 2*acc (bf16)
// MODE 1: fused epilogue -> out[bt][h][j] f32

template <int MODE>
__global__ __launch_bounds__(256, 3)
void cheb_gemm(const __bf16* __restrict__ Gb, const __bf16* __restrict__ Bmat,
               const __bf16* __restrict__ X0t, const __bf16* __restrict__ Wt,
               const float* __restrict__ bias, void* __restrict__ outp)
{
  __shared__ long long ldsraw[4096];   // 32 KB: [buf0: A 8K | B 8K][buf1: A 8K | B 8K]
  char* lds = (char*)ldsraw;

  const int tid = threadIdx.x;
  const int lane = tid & 63, wid = tid >> 6;
  const int l15 = lane & 15, lg = lane >> 4;
  const int wr = wid >> 1, wc = wid & 1;          // 2x2 wave grid, 64x64 per wave

  int bid = blockIdx.x;
  int lswz = (bid & 7) * 256 + (bid >> 3);        // XCD x -> one G row-panel (L2-resident)
  const int h0 = (lswz >> 8) * 128;
  const int n0 = (lswz & 255) * 128;

  auto stage = [&](int buf, int kt) {
    char* base = lds + buf * 16384;
    #pragma unroll
    for (int p = 0; p < 2; ++p) {
      int boff = tid * 16 + p * 4096;             // byte within 8 KB tile
      int row = boff >> 6, slot = (boff >> 4) & 3;
      const __bf16* ga = Gb + (size_t)(h0 + row) * 1024 + kt * 32 + slot * 8;
      GLOAD16(ga, base + wid * 1024 + p * 4096);
      const __bf16* gb = Bmat + (size_t)(n0 + row) * 1024 + kt * 32 + slot * 8;
      GLOAD16(gb, base + 8192 + wid * 1024 + p * 4096);
    }
  };

  const f32x4 zero = {0.f, 0.f, 0.f, 0.f};
  f32x4 acc[4][4];
  #pragma unroll
  for (int a = 0; a < 4; ++a)
    #pragma unroll
    for (int b2 = 0; b2 < 4; ++b2) acc[a][b2] = zero;

  stage(0, 0);
  __syncthreads();

  for (int kt = 0; kt < 32; ++kt) {
    int cur = kt & 1;
    if (kt < 31) stage(cur ^ 1, kt + 1);
    const __bf16* A = (const __bf16*)(lds + cur * 16384);
    const __bf16* Bl = A + 4096;
    bf16x8 af[4], bf[4];
    #pragma unroll
    for (int i = 0; i < 4; ++i) {
      af[i] = *reinterpret_cast<const bf16x8*>(&A[(wr * 64 + i * 16 + l15) * 32 + lg * 8]);
      bf[i] = *reinterpret_cast<const bf16x8*>(&Bl[(wc * 64 + i * 16 + l15) * 32 + lg * 8]);
    }
    #pragma unroll
    for (int a = 0; a < 4; ++a)
      #pragma unroll
      for (int b2 = 0; b2 < 4; ++b2)
        acc[a][b2] = MFMA16(af[a], bf[b2], acc[a][b2]);
    __syncthreads();
  }

  if (MODE == 0) {
    // X1t[n][h] = 2*acc  (bf16x4 stores: 4 consecutive h per lane)
    __bf16* X1t = (__bf16*)outp;
    #pragma unroll
    for (int a = 0; a < 4; ++a)
      #pragma unroll
      for (int b2 = 0; b2 < 4; ++b2) {
        bf16x4 p;
        #pragma unroll
        for (int q = 0; q < 4; ++q) p[q] = (__bf16)(2.0f * acc[a][b2][q]);
        size_t addr = (size_t)(n0 + wc * 64 + b2 * 16 + l15) * 1024
                      + h0 + wr * 64 + a * 16 + lg * 4;
        *reinterpret_cast<bf16x4*>(&X1t[addr]) = p;
      }
  } else {
    // acc = Z = 2*G*X1. out = X0*(W0-W2) + (2X1)*(W1/2) + Z*W2 + bias.
    // O^T = mfma(A=Wk rows j, B=Xk cols h, elems c): C row=j, col=h.
    float* out = (float*)outp;
    __bf16* Z = (__bf16*)(lds + wid * 4352);      // per-wave [32 c][68 pitch] bf16
    const int hb = h0 + wr * 64;

    #pragma unroll
    for (int blk = 0; blk < 2; ++blk) {
      // transpose-bounce this wave's Z block (32 c x 64 h) through LDS
      #pragma unroll
      for (int b2 = 0; b2 < 2; ++b2) {
        int c = b2 * 16 + l15;
        #pragma unroll
        for (int a = 0; a < 4; ++a) {
          f32x4 v = acc[a][blk * 2 + b2];
          bf16x4 p;
          #pragma unroll
          for (int q = 0; q < 4; ++q) p[q] = (__bf16)v[q];
          *reinterpret_cast<bf16x4*>(&Z[c * 68 + a * 16 + lg * 4]) = p;
        }
      }

      int btn = n0 + wc * 64 + blk * 32;          // global n of this bt-block's c=0
      f32x4 o[4][2];
      #pragma unroll
      for (int jg = 0; jg < 2; ++jg) {
        f32x4 bv = *reinterpret_cast<const f32x4*>(&bias[jg * 16 + lg * 4]);
        #pragma unroll
        for (int hg = 0; hg < 4; ++hg) o[hg][jg] = bv;
      }

      #pragma unroll
      for (int src = 0; src < 3; ++src) {
        bf16x8 w0 = *reinterpret_cast<const bf16x8*>(&Wt[src * 1024 + l15 * 32 + lg * 8]);
        bf16x8 w1 = *reinterpret_cast<const bf16x8*>(&Wt[src * 1024 + (16 + l15) * 32 + lg * 8]);
        const __bf16* xb = (src == 0) ? X0t : Bmat;
        #pragma unroll
        for (int hg = 0; hg < 4; ++hg) {
          bf16x8 bfr;
          if (src < 2) {
            const __bf16* p = xb + (size_t)(btn + lg * 8) * 1024 + hb + hg * 16 + l15;
            #pragma unroll
            for (int r = 0; r < 8; ++r) bfr[r] = p[(size_t)r * 1024];
          } else {
            #pragma unroll
            for (int r = 0; r < 8; ++r) bfr[r] = Z[(lg * 8 + r) * 68 + hg * 16 + l15];
          }
          o[hg][0] = MFMA16(w0, bfr, o[hg][0]);
          o[hg][1] = MFMA16(w1, bfr, o[hg][1]);
        }
      }

      size_t ob = (size_t)(btn >> 5) * 32768;
      #pragma unroll
      for (int hg = 0; hg < 4; ++hg)
        #pragma unroll
        for (int jg = 0; jg < 2; ++jg)
          *reinterpret_cast<f32x4*>(
              &out[ob + (size_t)(hb + hg * 16 + l15) * 32 + jg * 16 + lg * 4]) = o[hg][jg];
    }
  }
}

// ---------------- fallback: round-1 fused kernel (used if ws too small) ----------------

__device__ __forceinline__ int swz_f(int c, int i) {
  return (c << 10) + (i ^ ((c & 7) << 3));
}

__global__ void prep_w_f(const float* __restrict__ w, __bf16* __restrict__ wt) {
  int tid = blockIdx.x * 256 + threadIdx.x;
  if (tid < 3 * 32 * 32) {
    int k = tid >> 10, rem = tid & 1023;
    int j = rem >> 5, c = rem & 31;
    float s = (k == 1) ? 0.5f : 1.0f;
    wt[tid] = (__bf16)(w[(k * 32 + c) * 32 + j] * s);
  }
}

__global__ __launch_bounds__(512, 2)
void cheb_fused(const float* __restrict__ x, const __bf16* __restrict__ Gb,
                const __bf16* __restrict__ Wt, const float* __restrict__ bias,
                float* __restrict__ out)
{
  __shared__ __bf16 ldsX[32 * 1024];
  __shared__ __bf16 ldsY[32 * 1024];

  const int wg = blockIdx.x;
  const int b = wg >> 6, t = wg & 63;
  const int tid = threadIdx.x;
  const int lane = tid & 63;
  const int wid = tid >> 6;
  const int l15 = lane & 15;
  const int lg = lane >> 4;

  {
    const int c = tid >> 4;
    const int seg = tid & 15;
    const float* xr = x + (size_t)((b * 32 + c) * 64 + t) * 1024;
    #pragma unroll
    for (int g = 0; g < 8; ++g) {
      int i0 = g * 128 + seg * 8;
      float4 v0 = *reinterpret_cast<const float4*>(xr + i0);
      float4 v1 = *reinterpret_cast<const float4*>(xr + i0 + 4);
      bf16x8 h;
      h[0] = (__bf16)v0.x; h[1] = (__bf16)v0.y; h[2] = (__bf16)v0.z; h[3] = (__bf16)v0.w;
      h[4] = (__bf16)v1.x; h[5] = (__bf16)v1.y; h[6] = (__bf16)v1.z; h[7] = (__bf16)v1.w;
      *reinterpret_cast<bf16x8*>(&ldsX[swz_f(c, i0)]) = h;
    }
  }
  __syncthreads();

  const f32x4 zero = {0.f, 0.f, 0.f, 0.f};
  f32x4 acc[8][2];
  #pragma unroll
  for (int r = 0; r < 8; ++r) { acc[r][0] = zero; acc[r][1] = zero; }

  const __bf16* Ga = Gb + (size_t)(wid * 128 + l15) * 1024 + lg * 8;

  #pragma unroll 2
  for (int k = 0; k < 1024; k += 32) {
    bf16x8 bf0 = *reinterpret_cast<const bf16x8*>(&ldsX[swz_f(l15, k + lg * 8)]);
    bf16x8 bf1 = *reinterpret_cast<const bf16x8*>(&ldsX[swz_f(16 + l15, k + lg * 8)]);
    bf16x8 af[8];
    #pragma unroll
    for (int r = 0; r < 8; ++r)
      af[r] = *reinterpret_cast<const bf16x8*>(Ga + r * 16 * 1024 + k);
    #pragma unroll
    for (int r = 0; r < 8; ++r) {
      acc[r][0] = MFMA16(af[r], bf0, acc[r][0]);
      acc[r][1] = MFMA16(af[r], bf1, acc[r][1]);
    }
  }

  #pragma unroll
  for (int r = 0; r < 8; ++r) {
    int hb = wid * 128 + r * 16 + lg * 4;
    #pragma unroll
    for (int cf = 0; cf < 2; ++cf) {
      int c = cf * 16 + l15;
      bf16x4 p;
      #pragma unroll
      for (int q = 0; q < 4; ++q) p[q] = (__bf16)(2.0f * acc[r][cf][q]);
      *reinterpret_cast<bf16x4*>(&ldsY[swz_f(c, hb)]) = p;
    }
  }
  __syncthreads();

  #pragma unroll
  for (int r = 0; r < 8; ++r) {
    int hb = wid * 128 + r * 16 + lg * 4;
    #pragma unroll
    for (int cf = 0; cf < 2; ++cf) {
      int c = cf * 16 + l15;
      bf16x4 xv = *reinterpret_cast<const bf16x4*>(&ldsX[swz_f(c, hb)]);
      f32x4 a;
      #pragma unroll
      for (int q = 0; q < 4; ++q) a[q] = -(float)xv[q];
      acc[r][cf] = a;
    }
  }
  #pragma unroll 2
  for (int k = 0; k < 1024; k += 32) {
    bf16x8 bf0 = *reinterpret_cast<const bf16x8*>(&ldsY[swz_f(l15, k + lg * 8)]);
    bf16x8 bf1 = *reinterpret_cast<const bf16x8*>(&ldsY[swz_f(16 + l15, k + lg * 8)]);
    bf16x8 af[8];
    #pragma unroll
    for (int r = 0; r < 8; ++r)
      af[r] = *reinterpret_cast<const bf16x8*>(Ga + r * 16 * 1024 + k);
    #pragma unroll
    for (int r = 0; r < 8; ++r) {
      acc[r][0] = MFMA16(af[r], bf0, acc[r][0]);
      acc[r][1] = MFMA16(af[r], bf1, acc[r][1]);
    }
  }

  f32x4 oacc[8][2];
  {
    float b0 = bias[l15], b1 = bias[16 + l15];
    f32x4 v0 = {b0, b0, b0, b0}, v1 = {b1, b1, b1, b1};
    #pragma unroll
    for (int r = 0; r < 8; ++r) { oacc[r][0] = v0; oacc[r][1] = v1; }
  }

  auto contrib = [&](const __bf16* lds, const __bf16* wtk) {
    bf16x8 w0 = *reinterpret_cast<const bf16x8*>(wtk + l15 * 32 + lg * 8);
    bf16x8 w1 = *reinterpret_cast<const bf16x8*>(wtk + (16 + l15) * 32 + lg * 8);
    #pragma unroll
    for (int r = 0; r < 8; ++r) {
      int h = wid * 128 + r * 16 + l15;
      bf16x8 af;
      #pragma unroll
      for (int j = 0; j < 8; ++j) af[j] = lds[swz_f(lg * 8 + j, h)];
      oacc[r][0] = MFMA16(af, w0, oacc[r][0]);
      oacc[r][1] = MFMA16(af, w1, oacc[r][1]);
    }
  };

  contrib(ldsX, Wt);

  #pragma unroll
  for (int r = 0; r < 8; ++r) {
    int hb = wid * 128 + r * 16 + lg * 4;
    #pragma unroll
    for (int cf = 0; cf < 2; ++cf) {
      int c = cf * 16 + l15;
      bf16x4 p;
      #pragma unroll
      for (int q = 0; q < 4; ++q) p[q] = (__bf16)acc[r][cf][q];
      *reinterpret_cast<bf16x4*>(&ldsX[swz_f(c, hb)]) = p;
    }
  }

  contrib(ldsY, Wt + 1024);
  contrib(ldsX, Wt + 2048);

  float* ob = out + (size_t)wg * 32768;
  #pragma unroll
  for (int r = 0; r < 8; ++r) {
    int hb = wid * 128 + r * 16 + lg * 4;
    #pragma unroll
    for (int q = 0; q < 4; ++q) {
      ob[(hb + q) * 32 + l15] = oacc[r][0][q];
      ob[(hb + q) * 32 + 16 + l15] = oacc[r][1][q];
    }
  }
}

// ---------------- launch ----------------

extern "C" void kernel_launch(void* const* d_in, const int* in_sizes, int n_in,
                              void* d_out, int out_size, void* d_ws, size_t ws_size,
                              hipStream_t stream) {
  const float* x    = (const float*)d_in[0];
  const float* gso  = (const float*)d_in[1];
  const float* w    = (const float*)d_in[2];
  const float* bias = (const float*)d_in[3];
  float* out = (float*)d_out;

  const size_t GB_BYTES = 2097152;                 // 1M bf16
  const size_t WT_BYTES = 8192;
  const size_t XT_BYTES = (size_t)32768 * 1024 * 2; // 64 MB
  const size_t need = GB_BYTES + WT_BYTES + 2 * XT_BYTES;

  char* ws = (char*)d_ws;
  __bf16* Gb = (__bf16*)ws;

  if (ws_size >= need) {
    __bf16* Wt  = (__bf16*)(ws + GB_BYTES);
    __bf16* X0t = (__bf16*)(ws + GB_BYTES + WT_BYTES);
    __bf16* X1t = (__bf16*)(ws + GB_BYTES + WT_BYTES + XT_BYTES);

    prep_gso<<<1024, 256, 0, stream>>>(gso, Gb);
    prep_w3<<<12, 256, 0, stream>>>(w, Wt);
    k0_transpose<<<4096, 256, 0, stream>>>(x, X0t);
    cheb_gemm<0><<<2048, 256, 0, stream>>>(Gb, X0t, X0t, Wt, bias, (void*)X1t);
    cheb_gemm<1><<<2048, 256, 0, stream>>>(Gb, X1t, X0t, Wt, bias, (void*)out);
  } else {
    __bf16* Wt = Gb + 1024 * 1024;
    prep_gso<<<1024, 256, 0, stream>>>(gso, Gb);
    prep_w_f<<<12, 256, 0, stream>>>(w, Wt);
    cheb_fused<<<1024, 512, 0, stream>>>(x, Gb, Wt, bias, out);
  }
}

// Round 4
// 217.908 us; speedup vs baseline: 2.3590x; 1.2390x over previous
//
#include <hip/hip_runtime.h>

typedef __attribute__((ext_vector_type(4))) float f32x4;
typedef __attribute__((ext_vector_type(8))) __bf16 bf16x8;
typedef __attribute__((ext_vector_type(4))) __bf16 bf16x4;

#define MFMA16(a, b, c) __builtin_amdgcn_mfma_f32_16x16x32_bf16((a), (b), (c), 0, 0, 0)

typedef const __attribute__((address_space(1))) void* gas1_t;
typedef __attribute__((address_space(3))) void* las3_t;
#define GLOAD16(gp, lp) __builtin_amdgcn_global_load_lds((gas1_t)(gp), (las3_t)(lp), 16, 0, 0)

__device__ __forceinline__ unsigned short bfbits(float f) {
  __bf16 b = (__bf16)f;
  return *reinterpret_cast<unsigned short*>(&b);
}

// ---- swizzled 8KB tile: logical [128 rows][64 B], phys = pair-row + slot-XOR ----
// byte(row,kb) = (row>>1)*128 + s*16 + (kb&15),  s = ((row&1)*4 | kb>>4) ^ ((row>>1)&7)
// -> a wave's 16 consecutive-row b128 frag reads hit 8 distinct bank-quad slots.
__device__ __forceinline__ int tile_addr(int row, int kb) {
  int s = (((row & 1) << 2) | (kb >> 4)) ^ ((row >> 1) & 7);
  return ((row >> 1) << 7) | (s << 4) | (kb & 15);
}
// inverse: phys p in [0,8192), 16B-aligned -> (row, kb) whose data belongs there
__device__ __forceinline__ void tile_decode(int p, int& row, int& kb) {
  int pair = p >> 7;
  int sx = ((p >> 4) & 7) ^ (pair & 7);
  row = (pair << 1) | (sx >> 2);
  kb = (sx & 3) << 4;
}

// ---------------- prep: G -> Gb (bf16 row-major) + Gt (bf16 transposed) ----------------
__global__ __launch_bounds__(256)
void gprep(const float* __restrict__ g, __bf16* __restrict__ Gb, __bf16* __restrict__ Gt) {
  __shared__ __bf16 Lt[128 * 132];  // transposed stash [col][row], padded pitch
  int rb = blockIdx.x >> 3, cb = blockIdx.x & 7;
  int tid = threadIdx.x;
  #pragma unroll
  for (int it = 0; it < 16; ++it) {
    int idx = it * 256 + tid;         // over 128 rows x 32 float4
    int r = idx >> 5, c4 = idx & 31;
    float4 v = *reinterpret_cast<const float4*>(g + (size_t)(rb * 128 + r) * 1024 + cb * 128 + c4 * 4);
    bf16x4 h;
    h[0] = (__bf16)v.x; h[1] = (__bf16)v.y; h[2] = (__bf16)v.z; h[3] = (__bf16)v.w;
    *reinterpret_cast<bf16x4*>(Gb + (size_t)(rb * 128 + r) * 1024 + cb * 128 + c4 * 4) = h;
    #pragma unroll
    for (int e = 0; e < 4; ++e) Lt[(c4 * 4 + e) * 132 + r] = h[e];
  }
  __syncthreads();
  #pragma unroll
  for (int it = 0; it < 8; ++it) {
    int idx = it * 256 + tid;         // over 128 cols x 16 chunks-of-8
    int i = idx >> 4, ch = idx & 15;
    bf16x8 v;
    #pragma unroll
    for (int e = 0; e < 8; ++e) v[e] = Lt[i * 132 + ch * 8 + e];
    *reinterpret_cast<bf16x8*>(Gt + (size_t)(cb * 128 + i) * 1024 + rb * 128 + ch * 8) = v;
  }
}

// Wt[k][j][c]: k0 = W0 - W2 (Chebyshev -X0 fold), k1 = W1, k2 = 2*W2
__global__ void prep_w3(const float* __restrict__ w, __bf16* __restrict__ wt) {
  int tid = blockIdx.x * 256 + threadIdx.x;
  if (tid < 3072) {
    int k = tid >> 10, rem = tid & 1023, j = rem >> 5, c = rem & 31;
    float wk = w[k * 1024 + c * 32 + j];
    float v;
    if (k == 0)      v = wk - w[2 * 1024 + c * 32 + j];
    else if (k == 1) v = wk;
    else             v = 2.0f * wk;
    wt[tid] = (__bf16)v;
  }
}

// X0t[(b*64+t)*32 + c][i] = x[b][c][t][i]
__global__ __launch_bounds__(256) void k0_transpose(const float* __restrict__ x,
                                                    __bf16* __restrict__ X0t) {
  int n0 = blockIdx.x * 8;
  int tid = threadIdx.x;
  #pragma unroll
  for (int r = 0; r < 8; ++r) {
    int n = n0 + r;
    int b = n >> 11, t = (n >> 5) & 63, c = n & 31;
    const float* src = x + (size_t)((b * 32 + c) * 64 + t) * 1024;
    float4 v = *reinterpret_cast<const float4*>(&src[tid * 4]);
    bf16x4 p;
    p[0] = (__bf16)v.x; p[1] = (__bf16)v.y; p[2] = (__bf16)v.z; p[3] = (__bf16)v.w;
    *reinterpret_cast<bf16x4*>(&X0t[(size_t)n * 1024 + tid * 4]) = p;
  }
}

// ---------------- G^2: C[h][i] = sum_k Gb[h][k] * Gt[i][k] ----------------
__global__ __launch_bounds__(256, 2)
void gsq(const __bf16* __restrict__ Gb, const __bf16* __restrict__ Gt,
         __bf16* __restrict__ G2b) {
  __shared__ char lds[32768];  // dbuf: [A 8K | B 8K] x2
  const int tid = threadIdx.x;
  const int lane = tid & 63, wid = tid >> 6;
  const int l15 = lane & 15, lg = lane >> 4;
  const int wr = wid >> 1, wc = wid & 1;
  const int hb = (blockIdx.x >> 3) * 128, ib = (blockIdx.x & 7) * 128;

  int r0, kb0, r1, kb1;
  tile_decode(tid * 16, r0, kb0);          // first 4KB half of the 8KB tile
  tile_decode(tid * 16 + 4096, r1, kb1);   // second half (FIX: no &4095 mask)
  const char* A0 = (const char*)Gb + (size_t)hb * 2048;
  const char* B0 = (const char*)Gt + (size_t)ib * 2048;

  auto stage = [&](int buf, int kt) {
    char* base = lds + buf * 16384;
    size_t oA0 = (size_t)r0 * 2048 + kt * 64 + kb0;
    size_t oA1 = (size_t)r1 * 2048 + kt * 64 + kb1;
    GLOAD16(A0 + oA0, base + wid * 1024);
    GLOAD16(A0 + oA1, base + 4096 + wid * 1024);
    GLOAD16(B0 + oA0, base + 8192 + wid * 1024);
    GLOAD16(B0 + oA1, base + 12288 + wid * 1024);
  };

  const f32x4 zero = {0.f, 0.f, 0.f, 0.f};
  f32x4 acc[4][4];
  #pragma unroll
  for (int a = 0; a < 4; ++a)
    #pragma unroll
    for (int b = 0; b < 4; ++b) acc[a][b] = zero;

  stage(0, 0);
  __syncthreads();
  for (int kt = 0; kt < 32; ++kt) {
    int cur = kt & 1;
    if (kt < 31) stage(cur ^ 1, kt + 1);
    const char* A = lds + cur * 16384;
    const char* B = A + 8192;
    bf16x8 af[4], bf[4];
    #pragma unroll
    for (int i = 0; i < 4; ++i) {
      af[i] = *reinterpret_cast<const bf16x8*>(A + tile_addr(wr * 64 + i * 16 + l15, lg * 16));
      bf[i] = *reinterpret_cast<const bf16x8*>(B + tile_addr(wc * 64 + i * 16 + l15, lg * 16));
    }
    #pragma unroll
    for (int a = 0; a < 4; ++a)
      #pragma unroll
      for (int b = 0; b < 4; ++b) acc[a][b] = MFMA16(af[a], bf[b], acc[a][b]);
    __syncthreads();
  }
  #pragma unroll
  for (int a = 0; a < 4; ++a)
    #pragma unroll
    for (int b = 0; b < 4; ++b)
      #pragma unroll
      for (int q = 0; q < 4; ++q) {
        int h = hb + wr * 64 + a * 16 + lg * 4 + q;
        int i = ib + wc * 64 + b * 16 + l15;
        G2b[(size_t)h * 1024 + i] = (__bf16)acc[a][b][q];
      }
}

// ---------------- main: acc1=G*X0, acc2=G2*X0 per [128h x 128n] tile + fused epilogue ----------------
__global__ __launch_bounds__(256, 2)
void cheb_main(const __bf16* __restrict__ Gb, const __bf16* __restrict__ G2b,
               const __bf16* __restrict__ X0t, const __bf16* __restrict__ Wt,
               const float* __restrict__ bias, float* __restrict__ out)
{
  __shared__ char lds[49152];
  // main loop: buf0 @0 {A1,A2,B x8K}, buf1 @24576
  // epilogue:  X0tile @0 (32K), b1 @32768 (8K), b2 @40960 (8K)

  const int tid = threadIdx.x;
  const int lane = tid & 63, wid = tid >> 6;
  const int l15 = lane & 15, lg = lane >> 4;
  const int wr = wid >> 1, wc = wid & 1;

  const int ht = blockIdx.x & 7;        // XCD-resident G/G2 slice
  const int nt = blockIdx.x >> 3;

  int r0, kb0, r1, kb1;
  tile_decode(tid * 16, r0, kb0);          // FIX: no mask
  tile_decode(tid * 16 + 4096, r1, kb1);   // FIX: no mask

  const char* A1g = (const char*)Gb + (size_t)ht * 128 * 2048;
  const char* A2g = (const char*)G2b + (size_t)ht * 128 * 2048;
  const char* Bg  = (const char*)X0t + (size_t)nt * 128 * 2048;

  auto stage = [&](int buf, int kt) {
    char* base = lds + buf * 24576;
    size_t o0 = (size_t)r0 * 2048 + kt * 64 + kb0;
    size_t o1 = (size_t)r1 * 2048 + kt * 64 + kb1;
    GLOAD16(A1g + o0, base + wid * 1024);
    GLOAD16(A1g + o1, base + 4096 + wid * 1024);
    GLOAD16(A2g + o0, base + 8192 + wid * 1024);
    GLOAD16(A2g + o1, base + 12288 + wid * 1024);
    GLOAD16(Bg + o0, base + 16384 + wid * 1024);
    GLOAD16(Bg + o1, base + 20480 + wid * 1024);
  };

  const f32x4 zero = {0.f, 0.f, 0.f, 0.f};
  f32x4 acc1[4][4], acc2[4][4];
  #pragma unroll
  for (int a = 0; a < 4; ++a)
    #pragma unroll
    for (int b = 0; b < 4; ++b) { acc1[a][b] = zero; acc2[a][b] = zero; }

  stage(0, 0);
  __syncthreads();
  for (int kt = 0; kt < 32; ++kt) {
    int cur = kt & 1;
    if (kt < 31) stage(cur ^ 1, kt + 1);
    const char* A1 = lds + cur * 24576;
    const char* A2 = A1 + 8192;
    const char* Bt = A1 + 16384;
    bf16x8 a1[4], a2[4], bf[4];
    #pragma unroll
    for (int i = 0; i < 4; ++i) {
      a1[i] = *reinterpret_cast<const bf16x8*>(A1 + tile_addr(wr * 64 + i * 16 + l15, lg * 16));
      a2[i] = *reinterpret_cast<const bf16x8*>(A2 + tile_addr(wr * 64 + i * 16 + l15, lg * 16));
      bf[i] = *reinterpret_cast<const bf16x8*>(Bt + tile_addr(wc * 64 + i * 16 + l15, lg * 16));
    }
    #pragma unroll
    for (int a = 0; a < 4; ++a)
      #pragma unroll
      for (int b = 0; b < 4; ++b) {
        acc1[a][b] = MFMA16(a1[a], bf[b], acc1[a][b]);
        acc2[a][b] = MFMA16(a2[a], bf[b], acc2[a][b]);
      }
    __syncthreads();
  }

  // ---- epilogue ----
  // stage X0tile: [128 n-rows][256 B of h-cols], linear
  #pragma unroll
  for (int i = 0; i < 8; ++i) {
    int pbase = i * 4096 + wid * 1024;        // wave-uniform LDS dest (HW adds lane*16)
    int pb = pbase + lane * 16;               // this lane's dest byte
    int prow = pb >> 8, pcol = pb & 255;
    GLOAD16((const char*)X0t + (size_t)(nt * 128 + prow) * 2048 + ht * 256 + pcol,
            lds + pbase);
  }

  // preload weight frags + bias
  bf16x8 wf[3][2];
  #pragma unroll
  for (int s = 0; s < 3; ++s)
    #pragma unroll
    for (int jf = 0; jf < 2; ++jf)
      wf[s][jf] = *reinterpret_cast<const bf16x8*>(Wt + s * 1024 + (jf * 16 + l15) * 32 + lg * 8);
  float bv[2] = {bias[l15], bias[16 + l15]};

  #pragma unroll
  for (int bt = 0; bt < 4; ++bt) {
    if (bt > 0) __syncthreads();              // prev bt's reads done before overwrite
    // bounce this bt's acc columns -> b1/b2 as [128 h][32 c] swizzled tiles
    if (wc == (bt >> 1)) {
      #pragma unroll
      for (int a = 0; a < 4; ++a)
        #pragma unroll
        for (int bsel = 0; bsel < 2; ++bsel) {
          int b = ((bt & 1) << 1) | bsel;
          int cb = (bsel * 16 + l15) * 2;
          #pragma unroll
          for (int q = 0; q < 4; ++q) {
            int h = wr * 64 + a * 16 + lg * 4 + q;
            *reinterpret_cast<unsigned short*>(lds + 32768 + tile_addr(h, cb)) = bfbits(acc1[a][b][q]);
            *reinterpret_cast<unsigned short*>(lds + 40960 + tile_addr(h, cb)) = bfbits(acc2[a][b][q]);
          }
        }
    }
    __syncthreads();

    // D[h][j] = bias + X0*(W0-W2) + Y1*W1 + Y2*(2W2); wave owns h-slice wid*32
    f32x4 D[2][2];
    #pragma unroll
    for (int mf = 0; mf < 2; ++mf) {
      D[mf][0] = (f32x4){bv[0], bv[0], bv[0], bv[0]};
      D[mf][1] = (f32x4){bv[1], bv[1], bv[1], bv[1]};
    }
    #pragma unroll
    for (int mf = 0; mf < 2; ++mf) {
      int hx = wid * 32 + mf * 16 + l15;
      bf16x8 s0;
      #pragma unroll
      for (int i2 = 0; i2 < 8; ++i2)
        ((unsigned short*)&s0)[i2] =
            *reinterpret_cast<const unsigned short*>(lds + (bt * 32 + lg * 8 + i2) * 256 + hx * 2);
      bf16x8 s1 = *reinterpret_cast<const bf16x8*>(lds + 32768 + tile_addr(hx, lg * 16));
      bf16x8 s2 = *reinterpret_cast<const bf16x8*>(lds + 40960 + tile_addr(hx, lg * 16));
      #pragma unroll
      for (int jf = 0; jf < 2; ++jf) {
        D[mf][jf] = MFMA16(s0, wf[0][jf], D[mf][jf]);
        D[mf][jf] = MFMA16(s1, wf[1][jf], D[mf][jf]);
        D[mf][jf] = MFMA16(s2, wf[2][jf], D[mf][jf]);
      }
    }
    size_t ob = (size_t)(nt * 4 + bt) * 32768 + (size_t)(ht * 128 + wid * 32) * 32;
    #pragma unroll
    for (int mf = 0; mf < 2; ++mf)
      #pragma unroll
      for (int jf = 0; jf < 2; ++jf)
        #pragma unroll
        for (int q = 0; q < 4; ++q)
          out[ob + (size_t)(mf * 16 + lg * 4 + q) * 32 + jf * 16 + l15] = D[mf][jf][q];
  }
}

// ---------------- fallback (R1, proven): used if ws too small ----------------
__device__ __forceinline__ int swz_f(int c, int i) {
  return (c << 10) + (i ^ ((c & 7) << 3));
}
__global__ void prep_w_f(const float* __restrict__ w, __bf16* __restrict__ wt) {
  int tid = blockIdx.x * 256 + threadIdx.x;
  if (tid < 3 * 32 * 32) {
    int k = tid >> 10, rem = tid & 1023;
    int j = rem >> 5, c = rem & 31;
    float s = (k == 1) ? 0.5f : 1.0f;
    wt[tid] = (__bf16)(w[(k * 32 + c) * 32 + j] * s);
  }
}
__global__ __launch_bounds__(512, 2)
void cheb_fused(const float* __restrict__ x, const __bf16* __restrict__ Gb,
                const __bf16* __restrict__ Wt, const float* __restrict__ bias,
                float* __restrict__ out)
{
  __shared__ __bf16 ldsX[32 * 1024];
  __shared__ __bf16 ldsY[32 * 1024];
  const int wg = blockIdx.x;
  const int b = wg >> 6, t = wg & 63;
  const int tid = threadIdx.x;
  const int lane = tid & 63;
  const int wid = tid >> 6;
  const int l15 = lane & 15;
  const int lg = lane >> 4;
  {
    const int c = tid >> 4;
    const int seg = tid & 15;
    const float* xr = x + (size_t)((b * 32 + c) * 64 + t) * 1024;
    #pragma unroll
    for (int g = 0; g < 8; ++g) {
      int i0 = g * 128 + seg * 8;
      float4 v0 = *reinterpret_cast<const float4*>(xr + i0);
      float4 v1 = *reinterpret_cast<const float4*>(xr + i0 + 4);
      bf16x8 h;
      h[0] = (__bf16)v0.x; h[1] = (__bf16)v0.y; h[2] = (__bf16)v0.z; h[3] = (__bf16)v0.w;
      h[4] = (__bf16)v1.x; h[5] = (__bf16)v1.y; h[6] = (__bf16)v1.z; h[7] = (__bf16)v1.w;
      *reinterpret_cast<bf16x8*>(&ldsX[swz_f(c, i0)]) = h;
    }
  }
  __syncthreads();
  const f32x4 zero = {0.f, 0.f, 0.f, 0.f};
  f32x4 acc[8][2];
  #pragma unroll
  for (int r = 0; r < 8; ++r) { acc[r][0] = zero; acc[r][1] = zero; }
  const __bf16* Ga = Gb + (size_t)(wid * 128 + l15) * 1024 + lg * 8;
  #pragma unroll 2
  for (int k = 0; k < 1024; k += 32) {
    bf16x8 bf0 = *reinterpret_cast<const bf16x8*>(&ldsX[swz_f(l15, k + lg * 8)]);
    bf16x8 bf1 = *reinterpret_cast<const bf16x8*>(&ldsX[swz_f(16 + l15, k + lg * 8)]);
    bf16x8 af[8];
    #pragma unroll
    for (int r = 0; r < 8; ++r)
      af[r] = *reinterpret_cast<const bf16x8*>(Ga + r * 16 * 1024 + k);
    #pragma unroll
    for (int r = 0; r < 8; ++r) {
      acc[r][0] = MFMA16(af[r], bf0, acc[r][0]);
      acc[r][1] = MFMA16(af[r], bf1, acc[r][1]);
    }
  }
  #pragma unroll
  for (int r = 0; r < 8; ++r) {
    int hb = wid * 128 + r * 16 + lg * 4;
    #pragma unroll
    for (int cf = 0; cf < 2; ++cf) {
      int c = cf * 16 + l15;
      bf16x4 p;
      #pragma unroll
      for (int q = 0; q < 4; ++q) p[q] = (__bf16)(2.0f * acc[r][cf][q]);
      *reinterpret_cast<bf16x4*>(&ldsY[swz_f(c, hb)]) = p;
    }
  }
  __syncthreads();
  #pragma unroll
  for (int r = 0; r < 8; ++r) {
    int hb = wid * 128 + r * 16 + lg * 4;
    #pragma unroll
    for (int cf = 0; cf < 2; ++cf) {
      int c = cf * 16 + l15;
      bf16x4 xv = *reinterpret_cast<const bf16x4*>(&ldsX[swz_f(c, hb)]);
      f32x4 a;
      #pragma unroll
      for (int q = 0; q < 4; ++q) a[q] = -(float)xv[q];
      acc[r][cf] = a;
    }
  }
  #pragma unroll 2
  for (int k = 0; k < 1024; k += 32) {
    bf16x8 bf0 = *reinterpret_cast<const bf16x8*>(&ldsY[swz_f(l15, k + lg * 8)]);
    bf16x8 bf1 = *reinterpret_cast<const bf16x8*>(&ldsY[swz_f(16 + l15, k + lg * 8)]);
    bf16x8 af[8];
    #pragma unroll
    for (int r = 0; r < 8; ++r)
      af[r] = *reinterpret_cast<const bf16x8*>(Ga + r * 16 * 1024 + k);
    #pragma unroll
    for (int r = 0; r < 8; ++r) {
      acc[r][0] = MFMA16(af[r], bf0, acc[r][0]);
      acc[r][1] = MFMA16(af[r], bf1, acc[r][1]);
    }
  }
  f32x4 oacc[8][2];
  {
    float b0 = bias[l15], b1 = bias[16 + l15];
    f32x4 v0 = {b0, b0, b0, b0}, v1 = {b1, b1, b1, b1};
    #pragma unroll
    for (int r = 0; r < 8; ++r) { oacc[r][0] = v0; oacc[r][1] = v1; }
  }
  auto contrib = [&](const __bf16* lds, const __bf16* wtk) {
    bf16x8 w0 = *reinterpret_cast<const bf16x8*>(wtk + l15 * 32 + lg * 8);
    bf16x8 w1 = *reinterpret_cast<const bf16x8*>(wtk + (16 + l15) * 32 + lg * 8);
    #pragma unroll
    for (int r = 0; r < 8; ++r) {
      int h = wid * 128 + r * 16 + l15;
      bf16x8 af;
      #pragma unroll
      for (int j = 0; j < 8; ++j) af[j] = lds[swz_f(lg * 8 + j, h)];
      oacc[r][0] = MFMA16(af, w0, oacc[r][0]);
      oacc[r][1] = MFMA16(af, w1, oacc[r][1]);
    }
  };
  contrib(ldsX, Wt);
  #pragma unroll
  for (int r = 0; r < 8; ++r) {
    int hb = wid * 128 + r * 16 + lg * 4;
    #pragma unroll
    for (int cf = 0; cf < 2; ++cf) {
      int c = cf * 16 + l15;
      bf16x4 p;
      #pragma unroll
      for (int q = 0; q < 4; ++q) p[q] = (__bf16)acc[r][cf][q];
      *reinterpret_cast<bf16x4*>(&ldsX[swz_f(c, hb)]) = p;
    }
  }
  contrib(ldsY, Wt + 1024);
  contrib(ldsX, Wt + 2048);
  float* ob = out + (size_t)wg * 32768;
  #pragma unroll
  for (int r = 0; r < 8; ++r) {
    int hb = wid * 128 + r * 16 + lg * 4;
    #pragma unroll
    for (int q = 0; q < 4; ++q) {
      ob[(hb + q) * 32 + l15] = oacc[r][0][q];
      ob[(hb + q) * 32 + 16 + l15] = oacc[r][1][q];
    }
  }
}

// ---------------- launch ----------------
extern "C" void kernel_launch(void* const* d_in, const int* in_sizes, int n_in,
                              void* d_out, int out_size, void* d_ws, size_t ws_size,
                              hipStream_t stream) {
  const float* x    = (const float*)d_in[0];
  const float* gso  = (const float*)d_in[1];
  const float* w    = (const float*)d_in[2];
  const float* bias = (const float*)d_in[3];
  float* out = (float*)d_out;

  char* ws = (char*)d_ws;
  const size_t MB = 1024 * 1024;
  __bf16* Gb  = (__bf16*)(ws);                // 2 MB
  __bf16* Gt  = (__bf16*)(ws + 2 * MB);       // 2 MB
  __bf16* G2b = (__bf16*)(ws + 4 * MB);       // 2 MB
  __bf16* Wt  = (__bf16*)(ws + 6 * MB);       // 8 KB
  __bf16* X0t = (__bf16*)(ws + 8 * MB);       // 64 MB
  const size_t need = 8 * MB + 64 * MB;

  if (ws_size >= need) {
    gprep<<<64, 256, 0, stream>>>(gso, Gb, Gt);
    prep_w3<<<12, 256, 0, stream>>>(w, Wt);
    k0_transpose<<<4096, 256, 0, stream>>>(x, X0t);
    gsq<<<64, 256, 0, stream>>>(Gb, Gt, G2b);
    cheb_main<<<2048, 256, 0, stream>>>(Gb, G2b, X0t, Wt, bias, out);
  } else {
    __bf16* Wtf = (__bf16*)(ws + 6 * MB);
    gprep<<<64, 256, 0, stream>>>(gso, Gb, Gt);
    prep_w_f<<<12, 256, 0, stream>>>(w, Wtf);
    cheb_fused<<<1024, 512, 0, stream>>>(x, Gb, Wtf, bias, out);
  }
}